// Round 1
// baseline (1020.110 us; speedup 1.0000x reference)
//
#include <hip/hip_runtime.h>
#include <hip/hip_bf16.h>

#define NE 50000
#define NA 800000
#define NC 100000
#define FD 64
#define HD 128
#define NL 3

typedef _Float16 f16;
typedef f16 half8 __attribute__((ext_vector_type(8)));
typedef f16 half4 __attribute__((ext_vector_type(4)));
typedef float f32x4 __attribute__((ext_vector_type(4)));

// ---------------- weight transpose+convert: W[K][128] f32 -> Wt[128][K] f16 ----
struct WTArgs {
    const float* src[16];
    int K[16];
    int dstOff[16];
    int cum[17];
};

__global__ void convert_weights(WTArgs a, f16* __restrict__ wt) {
    int gid = blockIdx.x * 256 + threadIdx.x;
    if (gid >= a.cum[16]) return;
    int j = 0;
#pragma unroll
    for (int i = 1; i < 16; ++i) j += (gid >= a.cum[i]) ? 1 : 0;
    int e = gid - a.cum[j];
    int K = a.K[j];
    int k = e % K;
    int n = e / K;
    wt[a.dstOff[j] + n * K + k] = (f16)a.src[j][(size_t)k * 128 + n];
}

__global__ void convert_x(const float* __restrict__ x, f16* __restrict__ xb) {
    int i = blockIdx.x * 256 + threadIdx.x;
    if (i < NE * 16) {  // NE*64/4
        float4 v = ((const float4*)x)[i];
        half4 o = {(f16)v.x, (f16)v.y, (f16)v.z, (f16)v.w};
        ((half4*)xb)[i] = o;
    }
}

__global__ void deg_kernel(const int* __restrict__ adj_dst, float* __restrict__ deg) {
    int i = blockIdx.x * 256 + threadIdx.x;
    if (i < NA) unsafeAtomicAdd(&deg[adj_dst[i]], 1.0f);
}

__global__ void inv_kernel(const float* __restrict__ deg, float* __restrict__ inv,
                           int* __restrict__ isoList, int* __restrict__ isoCnt) {
    int i = blockIdx.x * 256 + threadIdx.x;
    if (i < NE) {
        float d = deg[i];
        inv[i] = 1.0f / fmaxf(d, 1.0f);
        if (d == 0.0f) {
            int p = atomicAdd(isoCnt, 1);
            isoList[p] = i;
        }
    }
}

__global__ void finalize_msg(const float* __restrict__ agg, const float* __restrict__ inv,
                             f16* __restrict__ msg) {
    int i = blockIdx.x * 256 + threadIdx.x;
    if (i < NE * 32) {  // NE*128/4
        int row = i >> 5;
        float s = inv[row];
        float4 v = ((const float4*)agg)[i];
        half4 o = {(f16)(v.x * s), (f16)(v.y * s), (f16)(v.z * s), (f16)(v.w * s)};
        ((half4*)msg)[i] = o;
    }
}

// scalar fallback: self-message for isolated nodes (expected count ~0)
__global__ void iso_fix(const int* __restrict__ isoList, const int* __restrict__ isoCnt,
                        const f16* __restrict__ e, const f16* __restrict__ w1t,
                        const float* __restrict__ b1, const f16* __restrict__ w2t,
                        const float* __restrict__ b2, f16* __restrict__ msg) {
    __shared__ float esh[128];
    __shared__ float hsh[128];
    int h = threadIdx.x;  // 128 threads
    int cnt = *isoCnt;
    for (int ii = blockIdx.x; ii < cnt; ii += gridDim.x) {
        int node = isoList[ii];
        esh[h] = (float)e[(size_t)node * 128 + h];
        __syncthreads();
        float s = b1[h];
        for (int k = 0; k < 128; ++k)
            s += esh[k] * ((float)w1t[h * 256 + k] + (float)w1t[h * 256 + 128 + k]);
        hsh[h] = fmaxf(s, 0.0f);
        __syncthreads();
        float o = b2[h];
        for (int k = 0; k < 128; ++k) o += hsh[k] * (float)w2t[h * 128 + k];
        msg[(size_t)node * 128 + h] = (f16)o;
        __syncthreads();
    }
}

// ---------------- the workhorse: 64-row tile, 2-layer MLP (K1 -> relu -> 128) ----
// MODE 0: pair-message. gather rows = concat(e[idx0[r]], e[idx1[r]]); segmented
//         atomic-add of output into agg[dst] (idx0 == adj_dst is SORTED).
// MODE 1: update. rows = concat(in0[r], in1[r]); outer relu; store f16 out.
// MODE 2: predictor. gather rows = concat(e[idx0], e[idx1]); relu; dot w3 + b3;
//         write sigmoid+logit.
// MODE 3: encoder. rows = in0[r] (K1=64); no outer relu; store f16 out.
template <int K1, int MODE>
__global__ __launch_bounds__(256, 2) void mlp_kernel(
    const f16* __restrict__ in0, const f16* __restrict__ in1,
    const int* __restrict__ idx0, const int* __restrict__ idx1,
    const f16* __restrict__ w1t, const float* __restrict__ b1,
    const f16* __restrict__ w2t, const float* __restrict__ b2,
    float* __restrict__ agg, f16* __restrict__ outh,
    const float* __restrict__ w3, const float* __restrict__ pb3,
    float* __restrict__ outProb, float* __restrict__ outLogit, int numRows) {
    constexpr int KC1 = K1 / 32;
    constexpr int SA = K1 + 8;   // f16 stride, 2-way LDS aliasing only (free)
    constexpr int SO = 133;      // f32 stride for staged output
    constexpr int SH = 136;      // f16 stride for hidden
    constexpr int ABYTES = (MODE == 0 || MODE == 2) ? (64 * SO * 4) : (64 * SA * 2);
    static_assert(ABYTES >= 64 * SA * 2 || !(MODE == 0 || MODE == 2), "alias size");
    __shared__ __align__(16) char AO[ABYTES];
    f16* Abuf = (f16*)AO;
    float* Obuf = (float*)AO;
    __shared__ __align__(16) f16 Hbuf[64 * SH];
    __shared__ int dstv[(MODE == 0) ? 64 : 1];
    __shared__ float w3s[(MODE == 2) ? 128 : 1];
    __shared__ float psum[(MODE == 2) ? 256 : 1];

    const int t = threadIdx.x;
    const int lane = t & 63;
    const int wave = t >> 6;
    const int quad = lane >> 4;
    const int mn = lane & 15;
    const int n0 = wave * 32;  // this wave's output-column base

    // persistent weight fragments: B[k][n] with n=lane&15, k=quad*8+j  ->  Wt[n][k]
    half8 w1f[KC1][2];
#pragma unroll
    for (int kc = 0; kc < KC1; ++kc)
#pragma unroll
        for (int nt = 0; nt < 2; ++nt)
            w1f[kc][nt] = *(const half8*)(w1t + (size_t)(n0 + nt * 16 + mn) * K1 + kc * 32 + quad * 8);
    half8 w2f[4][2];
#pragma unroll
    for (int kc = 0; kc < 4; ++kc)
#pragma unroll
        for (int nt = 0; nt < 2; ++nt)
            w2f[kc][nt] = *(const half8*)(w2t + (size_t)(n0 + nt * 16 + mn) * 128 + kc * 32 + quad * 8);
    float b1c[2] = {b1[n0 + mn], b1[n0 + 16 + mn]};
    float b2c[2] = {b2[n0 + mn], b2[n0 + 16 + mn]};
    float b3v = 0.0f;
    if constexpr (MODE == 2) {
        if (t < 128) w3s[t] = w3[t];
        b3v = pb3[0];
    }

    const int nTiles = (numRows + 63) >> 6;
    for (int tile = blockIdx.x; tile < nTiles; tile += gridDim.x) {
        const int rbase = tile << 6;
        const int valid = min(64, numRows - rbase);

        if constexpr (MODE == 0) {
            if (t < 64) dstv[t] = (rbase + t < numRows) ? idx0[rbase + t] : -1;
        }
        // ---- gather stage: 16B units into padded LDS tile
        constexpr int UPR = K1 / 8;             // 16B units per row
        constexpr int USH = (K1 == 256) ? 5 : 3;
#pragma unroll
        for (int it = 0; it < (64 * UPR) / 256; ++it) {
            int u = it * 256 + t;
            int row = u >> USH;
            int k = (u & (UPR - 1)) * 8;
            int gr = rbase + row;
            half8 v = {};
            if (gr < numRows) {
                const f16* src;
                if constexpr (MODE == 3)
                    src = in0 + (size_t)gr * 64 + k;
                else if constexpr (MODE == 1)
                    src = (k < 128) ? (in0 + (size_t)gr * 128 + k)
                                    : (in1 + (size_t)gr * 128 + (k - 128));
                else {
                    int ix = (k < 128) ? idx0[gr] : idx1[gr];
                    src = in0 + (size_t)ix * 128 + (k & 127);
                }
                v = *(const half8*)src;
            }
            *(half8*)(Abuf + row * SA + k) = v;
        }
        __syncthreads();

        // ---- GEMM1: [64 x K1] @ [K1 x 128], bias b1, relu
        f32x4 acc[4][2];
#pragma unroll
        for (int mt = 0; mt < 4; ++mt) {
            acc[mt][0] = (f32x4){b1c[0], b1c[0], b1c[0], b1c[0]};
            acc[mt][1] = (f32x4){b1c[1], b1c[1], b1c[1], b1c[1]};
        }
#pragma unroll
        for (int kc = 0; kc < KC1; ++kc) {
            half8 af[4];
#pragma unroll
            for (int mt = 0; mt < 4; ++mt)
                af[mt] = *(const half8*)(Abuf + (mt * 16 + mn) * SA + kc * 32 + quad * 8);
#pragma unroll
            for (int mt = 0; mt < 4; ++mt) {
                acc[mt][0] = __builtin_amdgcn_mfma_f32_16x16x32_f16(af[mt], w1f[kc][0], acc[mt][0], 0, 0, 0);
                acc[mt][1] = __builtin_amdgcn_mfma_f32_16x16x32_f16(af[mt], w1f[kc][1], acc[mt][1], 0, 0, 0);
            }
        }
        // hidden -> LDS (relu + f16).  C/D layout: col = lane&15, row = quad*4+reg
#pragma unroll
        for (int mt = 0; mt < 4; ++mt)
#pragma unroll
            for (int nt = 0; nt < 2; ++nt)
#pragma unroll
                for (int r = 0; r < 4; ++r)
                    Hbuf[(mt * 16 + quad * 4 + r) * SH + n0 + nt * 16 + mn] =
                        (f16)fmaxf(acc[mt][nt][r], 0.0f);
        __syncthreads();

        // ---- GEMM2: [64 x 128] @ [128 x 128], bias b2
        f32x4 acc2[4][2];
#pragma unroll
        for (int mt = 0; mt < 4; ++mt) {
            acc2[mt][0] = (f32x4){b2c[0], b2c[0], b2c[0], b2c[0]};
            acc2[mt][1] = (f32x4){b2c[1], b2c[1], b2c[1], b2c[1]};
        }
#pragma unroll
        for (int kc = 0; kc < 4; ++kc) {
            half8 af[4];
#pragma unroll
            for (int mt = 0; mt < 4; ++mt)
                af[mt] = *(const half8*)(Hbuf + (mt * 16 + mn) * SH + kc * 32 + quad * 8);
#pragma unroll
            for (int mt = 0; mt < 4; ++mt) {
                acc2[mt][0] = __builtin_amdgcn_mfma_f32_16x16x32_f16(af[mt], w2f[kc][0], acc2[mt][0], 0, 0, 0);
                acc2[mt][1] = __builtin_amdgcn_mfma_f32_16x16x32_f16(af[mt], w2f[kc][1], acc2[mt][1], 0, 0, 0);
            }
        }

        if constexpr (MODE == 0) {
            // stage msgs f32 to LDS, then segmented atomic reduce (adj_dst sorted)
#pragma unroll
            for (int mt = 0; mt < 4; ++mt)
#pragma unroll
                for (int nt = 0; nt < 2; ++nt)
#pragma unroll
                    for (int r = 0; r < 4; ++r)
                        Obuf[(mt * 16 + quad * 4 + r) * SO + n0 + nt * 16 + mn] = acc2[mt][nt][r];
            __syncthreads();
            {
                int c = t & 127, hf = t >> 7;
                int r0 = hf * 32, r1 = min(r0 + 32, valid);
                if (r0 < r1) {
                    float sum = 0.0f;
                    int prev = dstv[r0];
                    for (int r = r0; r < r1; ++r) {
                        int d = dstv[r];
                        if (d != prev) {
                            unsafeAtomicAdd(agg + (size_t)prev * 128 + c, sum);
                            sum = 0.0f;
                            prev = d;
                        }
                        sum += Obuf[r * SO + c];
                    }
                    unsafeAtomicAdd(agg + (size_t)prev * 128 + c, sum);
                }
            }
            __syncthreads();
        } else if constexpr (MODE == 1 || MODE == 3) {
#pragma unroll
            for (int mt = 0; mt < 4; ++mt)
#pragma unroll
                for (int nt = 0; nt < 2; ++nt)
#pragma unroll
                    for (int r = 0; r < 4; ++r) {
                        int gr = rbase + mt * 16 + quad * 4 + r;
                        if (gr < numRows) {
                            float v = acc2[mt][nt][r];
                            if constexpr (MODE == 1) v = fmaxf(v, 0.0f);
                            outh[(size_t)gr * 128 + n0 + nt * 16 + mn] = (f16)v;
                        }
                    }
        } else {  // MODE 2: predictor epilogue
#pragma unroll
            for (int mt = 0; mt < 4; ++mt)
#pragma unroll
                for (int nt = 0; nt < 2; ++nt)
#pragma unroll
                    for (int r = 0; r < 4; ++r)
                        Obuf[(mt * 16 + quad * 4 + r) * SO + n0 + nt * 16 + mn] =
                            fmaxf(acc2[mt][nt][r], 0.0f);
            __syncthreads();
            {
                int row = t & 63, q4 = t >> 6;  // q4 wave-uniform -> w3s broadcast
                float s = 0.0f;
#pragma unroll
                for (int i = 0; i < 32; ++i)
                    s += Obuf[row * SO + q4 * 32 + i] * w3s[q4 * 32 + i];
                psum[t] = s;
            }
            __syncthreads();
            if (t < 64) {
                int gr = rbase + t;
                if (gr < numRows) {
                    float lg = psum[t] + psum[t + 64] + psum[t + 128] + psum[t + 192] + b3v;
                    outLogit[gr] = lg;
                    outProb[gr] = 1.0f / (1.0f + expf(-lg));
                }
            }
            __syncthreads();
        }
    }
}

// ---------------- host ----------------
#define OFF_ENC1 0
#define OFF_ENC2 8192
#define OFF_MSG1 24576
#define OFF_MSG2 122880
#define OFF_UPD1 172032
#define OFF_UPD2 270336
#define OFF_PRED1 319488
#define OFF_PRED2 352256
#define TOTAL_WT 368640

extern "C" void kernel_launch(void* const* d_in, const int* in_sizes, int n_in,
                              void* d_out, int out_size, void* d_ws, size_t ws_size,
                              hipStream_t stream) {
    const float* edge_features = (const float*)d_in[0];
    const int* adj_dst = (const int*)d_in[1];
    const int* adj_src = (const int*)d_in[2];
    const int* cand_i = (const int*)d_in[3];
    const int* cand_j = (const int*)d_in[4];
    const float* enc_W1 = (const float*)d_in[5];
    const float* enc_b1 = (const float*)d_in[6];
    const float* enc_W2 = (const float*)d_in[7];
    const float* enc_b2 = (const float*)d_in[8];
    const float* msg_W1 = (const float*)d_in[9];
    const float* msg_b1 = (const float*)d_in[10];
    const float* msg_W2 = (const float*)d_in[11];
    const float* msg_b2 = (const float*)d_in[12];
    const float* upd_W1 = (const float*)d_in[13];
    const float* upd_b1 = (const float*)d_in[14];
    const float* upd_W2 = (const float*)d_in[15];
    const float* upd_b2 = (const float*)d_in[16];
    const float* pred_W1 = (const float*)d_in[17];
    const float* pred_b1 = (const float*)d_in[18];
    const float* pred_W2 = (const float*)d_in[19];
    const float* pred_b2 = (const float*)d_in[20];
    const float* pred_W3 = (const float*)d_in[21];
    const float* pred_b3 = (const float*)d_in[22];

    char* ws = (char*)d_ws;
    size_t off = 0;
    auto alloc = [&](size_t bytes) -> void* {
        void* p = ws + off;
        off = (off + bytes + 255) & ~(size_t)255;
        return p;
    };
    f16* wt = (f16*)alloc((size_t)TOTAL_WT * 2);
    f16* xb = (f16*)alloc((size_t)NE * 64 * 2);
    f16* eA = (f16*)alloc((size_t)NE * 128 * 2);
    f16* eB = (f16*)alloc((size_t)NE * 128 * 2);
    f16* msg = (f16*)alloc((size_t)NE * 128 * 2);
    float* agg = (float*)alloc((size_t)NE * 128 * 4);
    float* inv = (float*)alloc((size_t)NE * 4);
    float* deg = (float*)alloc((size_t)NE * 4);
    int* isoList = (int*)alloc((size_t)NE * 4);
    int* isoCnt = (int*)alloc(256);

    // weight conversion jobs
    WTArgs wa;
    int idx = 0, c = 0;
    auto addj = [&](const float* s, int K, int o) {
        wa.src[idx] = s; wa.K[idx] = K; wa.dstOff[idx] = o; wa.cum[idx] = c;
        c += K * 128; idx++;
    };
    addj(enc_W1, 64, OFF_ENC1);
    addj(enc_W2, 128, OFF_ENC2);
    for (int l = 0; l < 3; ++l) addj(msg_W1 + (size_t)l * 256 * 128, 256, OFF_MSG1 + l * 32768);
    for (int l = 0; l < 3; ++l) addj(msg_W2 + (size_t)l * 128 * 128, 128, OFF_MSG2 + l * 16384);
    for (int l = 0; l < 3; ++l) addj(upd_W1 + (size_t)l * 256 * 128, 256, OFF_UPD1 + l * 32768);
    for (int l = 0; l < 3; ++l) addj(upd_W2 + (size_t)l * 128 * 128, 128, OFF_UPD2 + l * 16384);
    addj(pred_W1, 256, OFF_PRED1);
    addj(pred_W2, 128, OFF_PRED2);
    wa.cum[16] = c;  // 368640

    convert_weights<<<(TOTAL_WT + 255) / 256, 256, 0, stream>>>(wa, wt);
    convert_x<<<(NE * 16 + 255) / 256, 256, 0, stream>>>(edge_features, xb);
    hipMemsetAsync(deg, 0, (size_t)NE * 4, stream);
    hipMemsetAsync(isoCnt, 0, 4, stream);
    deg_kernel<<<(NA + 255) / 256, 256, 0, stream>>>(adj_dst, deg);
    inv_kernel<<<(NE + 255) / 256, 256, 0, stream>>>(deg, inv, isoList, isoCnt);

    // encoder: e = mlp2(X)
    mlp_kernel<64, 3><<<512, 256, 0, stream>>>(xb, nullptr, nullptr, nullptr,
        wt + OFF_ENC1, enc_b1, wt + OFF_ENC2, enc_b2,
        nullptr, eA, nullptr, nullptr, nullptr, nullptr, NE);

    f16* cur = eA;
    f16* nxt = eB;
    for (int l = 0; l < NL; ++l) {
        hipMemsetAsync(agg, 0, (size_t)NE * 128 * 4, stream);
        mlp_kernel<256, 0><<<512, 256, 0, stream>>>(cur, nullptr, adj_dst, adj_src,
            wt + OFF_MSG1 + l * 32768, msg_b1 + l * 128,
            wt + OFF_MSG2 + l * 16384, msg_b2 + l * 128,
            agg, nullptr, nullptr, nullptr, nullptr, nullptr, NA);
        finalize_msg<<<(NE * 32 + 255) / 256, 256, 0, stream>>>(agg, inv, msg);
        iso_fix<<<64, 128, 0, stream>>>(isoList, isoCnt, cur,
            wt + OFF_MSG1 + l * 32768, msg_b1 + l * 128,
            wt + OFF_MSG2 + l * 16384, msg_b2 + l * 128, msg);
        mlp_kernel<256, 1><<<512, 256, 0, stream>>>(cur, msg, nullptr, nullptr,
            wt + OFF_UPD1 + l * 32768, upd_b1 + l * 128,
            wt + OFF_UPD2 + l * 16384, upd_b2 + l * 128,
            nullptr, nxt, nullptr, nullptr, nullptr, nullptr, NE);
        f16* tmp = cur; cur = nxt; nxt = tmp;
    }

    float* outP = (float*)d_out;
    mlp_kernel<256, 2><<<512, 256, 0, stream>>>(cur, nullptr, cand_i, cand_j,
        wt + OFF_PRED1, pred_b1, wt + OFF_PRED2, pred_b2,
        nullptr, nullptr, pred_W3, pred_b3, outP, outP + NC, NC);

    (void)in_sizes; (void)n_in; (void)out_size; (void)ws_size;
}

// Round 2
// 439.702 us; speedup vs baseline: 2.3200x; 2.3200x over previous
//
#include <hip/hip_runtime.h>
#include <hip/hip_bf16.h>

#define NE 50000
#define NA 800000
#define NC 100000

typedef _Float16 f16;
typedef f16 half8 __attribute__((ext_vector_type(8)));
typedef f16 f16x2 __attribute__((ext_vector_type(2)));
typedef float f32x4 __attribute__((ext_vector_type(4)));

// f16-element offsets inside the converted-weight arena
#define OFF_ENC1 0
#define OFF_ENC2 8192
#define OFF_MSGPQ 24576    // 3 layers x 32768 (P block 16384 + Q block 16384)
#define OFF_UPD1 122880    // 3 layers x 32768, fused layout [n][256]
#define OFF_UPD2 221184    // 3 layers x 16384
#define OFF_PREDPQ 270336  // 32768
#define OFF_PREDW2 303104  // 16384
#define TOTAL_WT 319488

// ---------------- weight transpose+convert: src W[K][128] f32 -> wt[n*stride + k] f16
struct WTArgs {
    const float* src[20];
    int K[20];
    int dstOff[20];
    int dstStride[20];
    int cum[21];
};

__global__ void convert_weights(WTArgs a, f16* __restrict__ wt) {
    int gid = blockIdx.x * 256 + threadIdx.x;
    if (gid >= a.cum[20]) return;
    int j = 0;
#pragma unroll
    for (int i = 1; i < 20; ++i) j += (gid >= a.cum[i]) ? 1 : 0;
    int e = gid - a.cum[j];
    int K = a.K[j];
    int k = e % K;
    int n = e / K;
    wt[a.dstOff[j] + n * a.dstStride[j] + k] = (f16)a.src[j][(size_t)k * 128 + n];
}

// W2U[l][k2][n] = sum_m msg_W2[l][k2][m] * upd_W1[l][128+m][n]  -> wt fused upd block
// fbias[l][n]   = upd_b1[l][n] + sum_m msg_b2[l][m] * upd_W1[l][128+m][n]
__global__ void fuse_w(const float* __restrict__ msg_W2, const float* __restrict__ msg_b2,
                       const float* __restrict__ upd_W1, const float* __restrict__ upd_b1,
                       f16* __restrict__ wt, float* __restrict__ fbias) {
    int gid = blockIdx.x * 256 + threadIdx.x;
    if (gid >= 3 * 128 * 129) return;
    int l = gid / (128 * 129);
    int rem = gid % (128 * 129);
    int n = rem / 129;
    int kk = rem % 129;
    const float* U1b = upd_W1 + (size_t)l * 32768 + 16384;  // [m][n]
    if (kk < 128) {
        const float* w2row = msg_W2 + (size_t)l * 16384 + (size_t)kk * 128;
        float s = 0.0f;
        for (int m = 0; m < 128; ++m) s += w2row[m] * U1b[m * 128 + n];
        wt[OFF_UPD1 + l * 32768 + n * 256 + 128 + kk] = (f16)s;
    } else {
        const float* b2 = msg_b2 + l * 128;
        float s = upd_b1[l * 128 + n];
        for (int m = 0; m < 128; ++m) s += b2[m] * U1b[m * 128 + n];
        fbias[l * 128 + n] = s;
    }
}

__global__ void convert_x(const float* __restrict__ x, f16* __restrict__ xb) {
    int i = blockIdx.x * 256 + threadIdx.x;
    if (i < NE * 16) {
        float4 v = ((const float4*)x)[i];
        f16 o0 = (f16)v.x, o1 = (f16)v.y, o2 = (f16)v.z, o3 = (f16)v.w;
        f16x2 a = {o0, o1}, b = {o2, o3};
        ((f16x2*)xb)[i * 2] = a;
        ((f16x2*)xb)[i * 2 + 1] = b;
    }
}

__global__ void deg_kernel(const int* __restrict__ adj_dst, int* __restrict__ degI) {
    int i = blockIdx.x * 256 + threadIdx.x;
    if (i < NA) atomicAdd(&degI[adj_dst[i]], 1);
}

// adj_dst is sorted: mark each segment's first row
__global__ void seg_kernel(const int* __restrict__ adj_dst, int* __restrict__ segStart) {
    int i = blockIdx.x * 256 + threadIdx.x;
    if (i < NA) {
        int d = adj_dst[i];
        if (i == 0 || adj_dst[i - 1] != d) segStart[d] = i;
    }
}

// ---------------- per-dst hidden aggregation: hbar[d] = inv_deg * sum_src relu(P[d]+Q[src])
// one wave per dst node; atomic-free (each dst owned by exactly one wave)
__global__ __launch_bounds__(256) void pair_agg(
    const f16* __restrict__ P, const f16* __restrict__ Q,
    const int* __restrict__ adj_src, const int* __restrict__ segStart,
    const int* __restrict__ degI, f16* __restrict__ hbar) {
    int w = __builtin_amdgcn_readfirstlane(blockIdx.x * 4 + (threadIdx.x >> 6));
    if (w >= NE) return;
    int lane = threadIdx.x & 63;
    f16x2 p2 = ((const f16x2*)P)[(size_t)w * 64 + lane];
    float p0 = (float)p2.x, p1 = (float)p2.y;
    float a0, a1;
    int deg = degI[w];
    if (deg == 0) {
        // isolated: self-message hidden relu(P[w] + Q[w])
        f16x2 q2 = ((const f16x2*)Q)[(size_t)w * 64 + lane];
        a0 = fmaxf(p0 + (float)q2.x, 0.0f);
        a1 = fmaxf(p1 + (float)q2.y, 0.0f);
    } else {
        int s = segStart[w];
        float x0 = 0.0f, x1 = 0.0f, y0 = 0.0f, y1 = 0.0f;
        int j = 0;
        for (; j + 1 < deg; j += 2) {
            int sa = adj_src[s + j];
            int sb = adj_src[s + j + 1];
            f16x2 qa = ((const f16x2*)Q)[(size_t)sa * 64 + lane];
            f16x2 qb = ((const f16x2*)Q)[(size_t)sb * 64 + lane];
            x0 += fmaxf(p0 + (float)qa.x, 0.0f);
            x1 += fmaxf(p1 + (float)qa.y, 0.0f);
            y0 += fmaxf(p0 + (float)qb.x, 0.0f);
            y1 += fmaxf(p1 + (float)qb.y, 0.0f);
        }
        if (j < deg) {
            int sa = adj_src[s + j];
            f16x2 qa = ((const f16x2*)Q)[(size_t)sa * 64 + lane];
            x0 += fmaxf(p0 + (float)qa.x, 0.0f);
            x1 += fmaxf(p1 + (float)qa.y, 0.0f);
        }
        float sc = 1.0f / (float)deg;
        a0 = (x0 + y0) * sc;
        a1 = (x1 + y1) * sc;
    }
    f16x2 o;
    o.x = (f16)a0;
    o.y = (f16)a1;
    ((f16x2*)hbar)[(size_t)w * 64 + lane] = o;
}

// ---------------- dual single-layer GEMM: P = e@W1a + b (waves 0-3), Q = e@W1b (waves 4-7)
__global__ __launch_bounds__(512, 2) void pq_kernel(
    const f16* __restrict__ ein, const f16* __restrict__ wpq,
    const float* __restrict__ bP,
    f16* __restrict__ P, f16* __restrict__ Q, int numRows) {
    constexpr int SA = 136;
    __shared__ __align__(16) f16 Abuf[64 * SA];
    const int t = threadIdx.x;
    const int lane = t & 63, wave = t >> 6;
    const int quad = lane >> 4, mn = lane & 15;
    const int sel = wave >> 2;
    const int n0 = (wave & 3) * 32;
    const f16* wt = wpq + (size_t)sel * 128 * 128;
    f16* out = sel ? Q : P;

    half8 wf[4][2];
#pragma unroll
    for (int kc = 0; kc < 4; ++kc)
#pragma unroll
        for (int nt = 0; nt < 2; ++nt)
            wf[kc][nt] = *(const half8*)(wt + (size_t)(n0 + nt * 16 + mn) * 128 + kc * 32 + quad * 8);
    float bc[2];
    bc[0] = sel ? 0.0f : bP[n0 + mn];
    bc[1] = sel ? 0.0f : bP[n0 + 16 + mn];

    const int nTiles = (numRows + 63) >> 6;
    for (int tile = blockIdx.x; tile < nTiles; tile += gridDim.x) {
        const int rbase = tile << 6;
#pragma unroll
        for (int it = 0; it < 2; ++it) {
            int u = it * 512 + t;
            int row = u >> 4;
            int k = (u & 15) * 8;
            int gr = rbase + row;
            half8 v = {};
            if (gr < numRows) v = *(const half8*)(ein + (size_t)gr * 128 + k);
            *(half8*)(Abuf + row * SA + k) = v;
        }
        __syncthreads();
        f32x4 acc[4][2];
#pragma unroll
        for (int mt = 0; mt < 4; ++mt) {
            acc[mt][0] = (f32x4){bc[0], bc[0], bc[0], bc[0]};
            acc[mt][1] = (f32x4){bc[1], bc[1], bc[1], bc[1]};
        }
#pragma unroll
        for (int kc = 0; kc < 4; ++kc) {
            half8 af[4];
#pragma unroll
            for (int mt = 0; mt < 4; ++mt)
                af[mt] = *(const half8*)(Abuf + (mt * 16 + mn) * SA + kc * 32 + quad * 8);
#pragma unroll
            for (int mt = 0; mt < 4; ++mt) {
                acc[mt][0] = __builtin_amdgcn_mfma_f32_16x16x32_f16(af[mt], wf[kc][0], acc[mt][0], 0, 0, 0);
                acc[mt][1] = __builtin_amdgcn_mfma_f32_16x16x32_f16(af[mt], wf[kc][1], acc[mt][1], 0, 0, 0);
            }
        }
#pragma unroll
        for (int mt = 0; mt < 4; ++mt)
#pragma unroll
            for (int nt = 0; nt < 2; ++nt)
#pragma unroll
                for (int r = 0; r < 4; ++r) {
                    int gr = rbase + mt * 16 + quad * 4 + r;
                    if (gr < numRows)
                        out[(size_t)gr * 128 + n0 + nt * 16 + mn] = (f16)acc[mt][nt][r];
                }
        __syncthreads();
    }
}

// ---------------- 2-layer MLP (K1 -> relu -> 128), Hbuf aliased into Abuf
template <int K1, bool RELU_OUT>
__global__ __launch_bounds__(256, 2) void mlp2_kernel(
    const f16* __restrict__ in0, const f16* __restrict__ in1,
    const f16* __restrict__ w1t, const float* __restrict__ b1,
    const f16* __restrict__ w2t, const float* __restrict__ b2,
    f16* __restrict__ outh, int numRows) {
    constexpr int KC1 = K1 / 32;
    constexpr int SA = K1 + 8;
    constexpr int SH = 136;
    constexpr int ABY = 64 * SA * 2;
    constexpr int HBY = 64 * SH * 2;
    constexpr int BYTES = ABY > HBY ? ABY : HBY;
    __shared__ __align__(16) char U[BYTES];
    f16* Abuf = (f16*)U;
    f16* Hbuf = (f16*)U;

    const int t = threadIdx.x;
    const int lane = t & 63, wave = t >> 6;
    const int quad = lane >> 4, mn = lane & 15;
    const int n0 = wave * 32;

    half8 w1f[KC1][2];
#pragma unroll
    for (int kc = 0; kc < KC1; ++kc)
#pragma unroll
        for (int nt = 0; nt < 2; ++nt)
            w1f[kc][nt] = *(const half8*)(w1t + (size_t)(n0 + nt * 16 + mn) * K1 + kc * 32 + quad * 8);
    half8 w2f[4][2];
#pragma unroll
    for (int kc = 0; kc < 4; ++kc)
#pragma unroll
        for (int nt = 0; nt < 2; ++nt)
            w2f[kc][nt] = *(const half8*)(w2t + (size_t)(n0 + nt * 16 + mn) * 128 + kc * 32 + quad * 8);
    float b1c[2] = {b1[n0 + mn], b1[n0 + 16 + mn]};
    float b2c[2] = {b2[n0 + mn], b2[n0 + 16 + mn]};

    const int nTiles = (numRows + 63) >> 6;
    for (int tile = blockIdx.x; tile < nTiles; tile += gridDim.x) {
        const int rbase = tile << 6;
        constexpr int UPR = K1 / 8;
        constexpr int USH = (K1 == 256) ? 5 : 3;
#pragma unroll
        for (int it = 0; it < (64 * UPR) / 256; ++it) {
            int u = it * 256 + t;
            int row = u >> USH;
            int k = (u & (UPR - 1)) * 8;
            int gr = rbase + row;
            half8 v = {};
            if (gr < numRows) {
                const f16* src;
                if constexpr (K1 == 64)
                    src = in0 + (size_t)gr * 64 + k;
                else
                    src = (k < 128) ? (in0 + (size_t)gr * 128 + k)
                                    : (in1 + (size_t)gr * 128 + (k - 128));
                v = *(const half8*)src;
            }
            *(half8*)(Abuf + row * SA + k) = v;
        }
        __syncthreads();

        f32x4 acc[4][2];
#pragma unroll
        for (int mt = 0; mt < 4; ++mt) {
            acc[mt][0] = (f32x4){b1c[0], b1c[0], b1c[0], b1c[0]};
            acc[mt][1] = (f32x4){b1c[1], b1c[1], b1c[1], b1c[1]};
        }
#pragma unroll
        for (int kc = 0; kc < KC1; ++kc) {
            half8 af[4];
#pragma unroll
            for (int mt = 0; mt < 4; ++mt)
                af[mt] = *(const half8*)(Abuf + (mt * 16 + mn) * SA + kc * 32 + quad * 8);
#pragma unroll
            for (int mt = 0; mt < 4; ++mt) {
                acc[mt][0] = __builtin_amdgcn_mfma_f32_16x16x32_f16(af[mt], w1f[kc][0], acc[mt][0], 0, 0, 0);
                acc[mt][1] = __builtin_amdgcn_mfma_f32_16x16x32_f16(af[mt], w1f[kc][1], acc[mt][1], 0, 0, 0);
            }
        }
        __syncthreads();  // Abuf reads complete before aliased Hbuf writes
#pragma unroll
        for (int mt = 0; mt < 4; ++mt)
#pragma unroll
            for (int nt = 0; nt < 2; ++nt)
#pragma unroll
                for (int r = 0; r < 4; ++r)
                    Hbuf[(mt * 16 + quad * 4 + r) * SH + n0 + nt * 16 + mn] =
                        (f16)fmaxf(acc[mt][nt][r], 0.0f);
        __syncthreads();

        f32x4 acc2[4][2];
#pragma unroll
        for (int mt = 0; mt < 4; ++mt) {
            acc2[mt][0] = (f32x4){b2c[0], b2c[0], b2c[0], b2c[0]};
            acc2[mt][1] = (f32x4){b2c[1], b2c[1], b2c[1], b2c[1]};
        }
#pragma unroll
        for (int kc = 0; kc < 4; ++kc) {
            half8 af[4];
#pragma unroll
            for (int mt = 0; mt < 4; ++mt)
                af[mt] = *(const half8*)(Hbuf + (mt * 16 + mn) * SH + kc * 32 + quad * 8);
#pragma unroll
            for (int mt = 0; mt < 4; ++mt) {
                acc2[mt][0] = __builtin_amdgcn_mfma_f32_16x16x32_f16(af[mt], w2f[kc][0], acc2[mt][0], 0, 0, 0);
                acc2[mt][1] = __builtin_amdgcn_mfma_f32_16x16x32_f16(af[mt], w2f[kc][1], acc2[mt][1], 0, 0, 0);
            }
        }
#pragma unroll
        for (int mt = 0; mt < 4; ++mt)
#pragma unroll
            for (int nt = 0; nt < 2; ++nt)
#pragma unroll
                for (int r = 0; r < 4; ++r) {
                    int gr = rbase + mt * 16 + quad * 4 + r;
                    if (gr < numRows) {
                        float v = acc2[mt][nt][r];
                        if constexpr (RELU_OUT) v = fmaxf(v, 0.0f);
                        outh[(size_t)gr * 128 + n0 + nt * 16 + mn] = (f16)v;
                    }
                }
        __syncthreads();  // Hbuf reads complete before next tile's stage
    }
}

// ---------------- predictor tail: h1=relu(Pp[i]+Qp[j]); h2=relu(h1@W2+b2); logit=h2@W3+b3
__global__ __launch_bounds__(256, 2) void pred_tail(
    const f16* __restrict__ Pp, const f16* __restrict__ Qp,
    const int* __restrict__ ci, const int* __restrict__ cj,
    const f16* __restrict__ w2t, const float* __restrict__ b2,
    const float* __restrict__ w3, const float* __restrict__ b3,
    float* __restrict__ outProb, float* __restrict__ outLogit, int numRows) {
    constexpr int SA = 136;  // f16
    constexpr int SO = 133;  // f32
    constexpr int BYTES = (64 * SO * 4 > 64 * SA * 2) ? 64 * SO * 4 : 64 * SA * 2;
    __shared__ __align__(16) char U[BYTES];
    f16* Abuf = (f16*)U;
    float* Obuf = (float*)U;
    __shared__ float w3s[128];
    __shared__ float psum[256];

    const int t = threadIdx.x;
    const int lane = t & 63, wave = t >> 6;
    const int quad = lane >> 4, mn = lane & 15;
    const int n0 = wave * 32;

    if (t < 128) w3s[t] = w3[t];
    float b3v = b3[0];

    half8 wf[4][2];
#pragma unroll
    for (int kc = 0; kc < 4; ++kc)
#pragma unroll
        for (int nt = 0; nt < 2; ++nt)
            wf[kc][nt] = *(const half8*)(w2t + (size_t)(n0 + nt * 16 + mn) * 128 + kc * 32 + quad * 8);
    float b2c[2] = {b2[n0 + mn], b2[n0 + 16 + mn]};

    const int nTiles = (numRows + 63) >> 6;
    for (int tile = blockIdx.x; tile < nTiles; tile += gridDim.x) {
        const int rbase = tile << 6;
#pragma unroll
        for (int it = 0; it < 4; ++it) {
            int u = it * 256 + t;
            int row = u >> 4;
            int k = (u & 15) * 8;
            int gr = rbase + row;
            half8 v = {};
            if (gr < numRows) {
                int i = ci[gr], j = cj[gr];
                half8 a = *(const half8*)(Pp + (size_t)i * 128 + k);
                half8 b = *(const half8*)(Qp + (size_t)j * 128 + k);
#pragma unroll
                for (int x = 0; x < 8; ++x)
                    v[x] = (f16)fmaxf((float)a[x] + (float)b[x], 0.0f);
            }
            *(half8*)(Abuf + row * SA + k) = v;
        }
        __syncthreads();

        f32x4 acc[4][2];
#pragma unroll
        for (int mt = 0; mt < 4; ++mt) {
            acc[mt][0] = (f32x4){b2c[0], b2c[0], b2c[0], b2c[0]};
            acc[mt][1] = (f32x4){b2c[1], b2c[1], b2c[1], b2c[1]};
        }
#pragma unroll
        for (int kc = 0; kc < 4; ++kc) {
            half8 af[4];
#pragma unroll
            for (int mt = 0; mt < 4; ++mt)
                af[mt] = *(const half8*)(Abuf + (mt * 16 + mn) * SA + kc * 32 + quad * 8);
#pragma unroll
            for (int mt = 0; mt < 4; ++mt) {
                acc[mt][0] = __builtin_amdgcn_mfma_f32_16x16x32_f16(af[mt], wf[kc][0], acc[mt][0], 0, 0, 0);
                acc[mt][1] = __builtin_amdgcn_mfma_f32_16x16x32_f16(af[mt], wf[kc][1], acc[mt][1], 0, 0, 0);
            }
        }
        __syncthreads();  // Abuf reads done before aliased Obuf writes
#pragma unroll
        for (int mt = 0; mt < 4; ++mt)
#pragma unroll
            for (int nt = 0; nt < 2; ++nt)
#pragma unroll
                for (int r = 0; r < 4; ++r)
                    Obuf[(mt * 16 + quad * 4 + r) * SO + n0 + nt * 16 + mn] =
                        fmaxf(acc[mt][nt][r], 0.0f);
        __syncthreads();
        {
            int row = t & 63, q4 = t >> 6;
            float s = 0.0f;
#pragma unroll
            for (int i = 0; i < 32; ++i)
                s += Obuf[row * SO + q4 * 32 + i] * w3s[q4 * 32 + i];
            psum[t] = s;
        }
        __syncthreads();
        if (t < 64) {
            int gr = rbase + t;
            if (gr < numRows) {
                float lg = psum[t] + psum[t + 64] + psum[t + 128] + psum[t + 192] + b3v;
                outLogit[gr] = lg;
                outProb[gr] = 1.0f / (1.0f + expf(-lg));
            }
        }
        __syncthreads();
    }
}

// ---------------- host ----------------
extern "C" void kernel_launch(void* const* d_in, const int* in_sizes, int n_in,
                              void* d_out, int out_size, void* d_ws, size_t ws_size,
                              hipStream_t stream) {
    const float* edge_features = (const float*)d_in[0];
    const int* adj_dst = (const int*)d_in[1];
    const int* adj_src = (const int*)d_in[2];
    const int* cand_i = (const int*)d_in[3];
    const int* cand_j = (const int*)d_in[4];
    const float* enc_W1 = (const float*)d_in[5];
    const float* enc_b1 = (const float*)d_in[6];
    const float* enc_W2 = (const float*)d_in[7];
    const float* enc_b2 = (const float*)d_in[8];
    const float* msg_W1 = (const float*)d_in[9];
    const float* msg_b1 = (const float*)d_in[10];
    const float* msg_W2 = (const float*)d_in[11];
    const float* msg_b2 = (const float*)d_in[12];
    const float* upd_W1 = (const float*)d_in[13];
    const float* upd_b1 = (const float*)d_in[14];
    const float* upd_W2 = (const float*)d_in[15];
    const float* upd_b2 = (const float*)d_in[16];
    const float* pred_W1 = (const float*)d_in[17];
    const float* pred_b1 = (const float*)d_in[18];
    const float* pred_W2 = (const float*)d_in[19];
    const float* pred_b2 = (const float*)d_in[20];
    const float* pred_W3 = (const float*)d_in[21];
    const float* pred_b3 = (const float*)d_in[22];

    char* ws = (char*)d_ws;
    size_t off = 0;
    auto alloc = [&](size_t bytes) -> void* {
        void* p = ws + off;
        off = (off + bytes + 255) & ~(size_t)255;
        return p;
    };
    f16* wt = (f16*)alloc((size_t)TOTAL_WT * 2);
    float* fbias = (float*)alloc(3 * 128 * 4);
    f16* xb = (f16*)alloc((size_t)NE * 64 * 2);
    f16* eA = (f16*)alloc((size_t)NE * 128 * 2);
    f16* eB = (f16*)alloc((size_t)NE * 128 * 2);
    f16* Pb = (f16*)alloc((size_t)NE * 128 * 2);
    f16* Qb = (f16*)alloc((size_t)NE * 128 * 2);
    f16* hbar = (f16*)alloc((size_t)NE * 128 * 2);
    int* degI = (int*)alloc((size_t)NE * 4);
    int* segStart = (int*)alloc((size_t)NE * 4);

    WTArgs wa;
    int idx = 0, c = 0;
    auto addj = [&](const float* s, int K, int o, int st) {
        wa.src[idx] = s; wa.K[idx] = K; wa.dstOff[idx] = o;
        wa.dstStride[idx] = st; wa.cum[idx] = c;
        c += K * 128; idx++;
    };
    addj(enc_W1, 64, OFF_ENC1, 64);
    addj(enc_W2, 128, OFF_ENC2, 128);
    for (int l = 0; l < 3; ++l) addj(msg_W1 + (size_t)l * 32768, 128, OFF_MSGPQ + l * 32768, 128);
    for (int l = 0; l < 3; ++l) addj(msg_W1 + (size_t)l * 32768 + 16384, 128, OFF_MSGPQ + l * 32768 + 16384, 128);
    for (int l = 0; l < 3; ++l) addj(upd_W1 + (size_t)l * 32768, 128, OFF_UPD1 + l * 32768, 256);
    for (int l = 0; l < 3; ++l) addj(upd_W2 + (size_t)l * 16384, 128, OFF_UPD2 + l * 16384, 128);
    addj(pred_W1, 128, OFF_PREDPQ, 128);
    addj(pred_W1 + 16384, 128, OFF_PREDPQ + 16384, 128);
    addj(pred_W2, 128, OFF_PREDW2, 128);
    for (int i = idx; i <= 20; ++i) wa.cum[i] = c;  // c == 270336

    convert_weights<<<(270336 + 255) / 256, 256, 0, stream>>>(wa, wt);
    fuse_w<<<(3 * 128 * 129 + 255) / 256, 256, 0, stream>>>(msg_W2, msg_b2, upd_W1, upd_b1, wt, fbias);
    convert_x<<<(NE * 16 + 255) / 256, 256, 0, stream>>>(edge_features, xb);
    hipMemsetAsync(degI, 0, (size_t)NE * 4, stream);
    deg_kernel<<<(NA + 255) / 256, 256, 0, stream>>>(adj_dst, degI);
    seg_kernel<<<(NA + 255) / 256, 256, 0, stream>>>(adj_dst, segStart);

    const int tilesNE = (NE + 63) / 64;  // 782
    mlp2_kernel<64, false><<<tilesNE, 256, 0, stream>>>(
        xb, nullptr, wt + OFF_ENC1, enc_b1, wt + OFF_ENC2, enc_b2, eA, NE);

    f16* cur = eA;
    f16* nxt = eB;
    for (int l = 0; l < 3; ++l) {
        pq_kernel<<<tilesNE, 512, 0, stream>>>(
            cur, wt + OFF_MSGPQ + l * 32768, msg_b1 + l * 128, Pb, Qb, NE);
        pair_agg<<<(NE + 3) / 4, 256, 0, stream>>>(Pb, Qb, adj_src, segStart, degI, hbar);
        mlp2_kernel<256, true><<<tilesNE, 256, 0, stream>>>(
            cur, hbar, wt + OFF_UPD1 + l * 32768, fbias + l * 128,
            wt + OFF_UPD2 + l * 16384, upd_b2 + l * 128, nxt, NE);
        f16* tmp = cur; cur = nxt; nxt = tmp;
    }

    float* outP = (float*)d_out;
    pq_kernel<<<tilesNE, 512, 0, stream>>>(
        cur, wt + OFF_PREDPQ, pred_b1, Pb, Qb, NE);
    pred_tail<<<(NC + 63) / 64, 256, 0, stream>>>(
        Pb, Qb, cand_i, cand_j, wt + OFF_PREDW2, pred_b2, pred_W3, pred_b3,
        outP, outP + NC, NC);

    (void)in_sizes; (void)n_in; (void)out_size; (void)ws_size;
}

// Round 3
// 392.919 us; speedup vs baseline: 2.5962x; 1.1191x over previous
//
#include <hip/hip_runtime.h>
#include <hip/hip_bf16.h>

#define NE 50000
#define NA 800000
#define NC 100000

typedef _Float16 f16;
typedef f16 half8 __attribute__((ext_vector_type(8)));
typedef f16 f16x2 __attribute__((ext_vector_type(2)));
typedef float f32x4 __attribute__((ext_vector_type(4)));

// f16-element offsets inside the converted-weight arena
#define OFF_ENC1 0
#define OFF_ENC2 8192
#define OFF_MSGPQ 24576    // 3 layers x 32768 (P block 16384 + Q block 16384)
#define OFF_UPD1 122880    // 3 layers x 32768, fused layout [n][256]
#define OFF_UPD2 221184    // 3 layers x 16384
#define OFF_PREDPQ 270336  // 32768
#define OFF_PREDW2 303104  // 16384
#define TOTAL_WT 319488

// ---------------- prep: weight transpose+convert + x convert + degI zero ----
struct WTArgs {
    const float* src[20];
    int K[20];
    int dstOff[20];
    int dstStride[20];
    int cum[21];
};

__global__ void prep_kernel(WTArgs a, const float* __restrict__ x,
                            f16* __restrict__ wt, f16* __restrict__ xb,
                            int* __restrict__ degI) {
    int gid = blockIdx.x * 256 + threadIdx.x;
    if (gid < a.cum[20]) {
        int j = 0;
#pragma unroll
        for (int i = 1; i < 20; ++i) j += (gid >= a.cum[i]) ? 1 : 0;
        int e = gid - a.cum[j];
        int K = a.K[j];
        int k = e % K;
        int n = e / K;
        wt[a.dstOff[j] + n * a.dstStride[j] + k] = (f16)a.src[j][(size_t)k * 128 + n];
        return;
    }
    int g2 = gid - a.cum[20];
    if (g2 < NE * 16) {
        float4 v = ((const float4*)x)[g2];
        f16x2 p = {(f16)v.x, (f16)v.y}, q = {(f16)v.z, (f16)v.w};
        ((f16x2*)xb)[g2 * 2] = p;
        ((f16x2*)xb)[g2 * 2 + 1] = q;
        return;
    }
    int g3 = g2 - NE * 16;
    if (g3 < NE) degI[g3] = 0;
}

// W2U[l][k2][n] = sum_m msg_W2[l][k2][m] * upd_W1[l][128+m][n]  -> fused upd block
// fbias[l][n]   = upd_b1[l][n] + sum_m msg_b2[l][m] * upd_W1[l][128+m][n]
__global__ void fuse_w(const float* __restrict__ msg_W2, const float* __restrict__ msg_b2,
                       const float* __restrict__ upd_W1, const float* __restrict__ upd_b1,
                       f16* __restrict__ wt, float* __restrict__ fbias) {
    int gid = blockIdx.x * 256 + threadIdx.x;
    if (gid >= 3 * 128 * 129) return;
    int l = gid / (128 * 129);
    int rem = gid % (128 * 129);
    int n = rem / 129;
    int kk = rem % 129;
    const float* U1b = upd_W1 + (size_t)l * 32768 + 16384;  // [m][n]
    if (kk < 128) {
        const float* w2row = msg_W2 + (size_t)l * 16384 + (size_t)kk * 128;
        float s = 0.0f;
        for (int m = 0; m < 128; ++m) s += w2row[m] * U1b[m * 128 + n];
        wt[OFF_UPD1 + l * 32768 + n * 256 + 128 + kk] = (f16)s;
    } else {
        const float* b2 = msg_b2 + l * 128;
        float s = upd_b1[l * 128 + n];
        for (int m = 0; m < 128; ++m) s += b2[m] * U1b[m * 128 + n];
        fbias[l * 128 + n] = s;
    }
}

// deg (atomic) + segment starts (adj_dst sorted) in one pass
__global__ void degseg_kernel(const int* __restrict__ adj_dst, int* __restrict__ degI,
                              int* __restrict__ segStart) {
    int i = blockIdx.x * 256 + threadIdx.x;
    if (i < NA) {
        int d = adj_dst[i];
        atomicAdd(&degI[d], 1);
        if (i == 0 || adj_dst[i - 1] != d) segStart[d] = i;
    }
}

// ---------------- per-dst hidden aggregation: hbar[d] = inv_deg * sum_src relu(P[d]+Q[src])
__global__ __launch_bounds__(256) void pair_agg(
    const f16* __restrict__ P, const f16* __restrict__ Q,
    const int* __restrict__ adj_src, const int* __restrict__ segStart,
    const int* __restrict__ degI, f16* __restrict__ hbar) {
    int w = __builtin_amdgcn_readfirstlane(blockIdx.x * 4 + (threadIdx.x >> 6));
    if (w >= NE) return;
    int lane = threadIdx.x & 63;
    f16x2 p2 = ((const f16x2*)P)[(size_t)w * 64 + lane];
    float p0 = (float)p2.x, p1 = (float)p2.y;
    float a0, a1;
    int deg = degI[w];
    if (deg == 0) {
        f16x2 q2 = ((const f16x2*)Q)[(size_t)w * 64 + lane];
        a0 = fmaxf(p0 + (float)q2.x, 0.0f);
        a1 = fmaxf(p1 + (float)q2.y, 0.0f);
    } else {
        int s = segStart[w];
        float x0 = 0.0f, x1 = 0.0f, y0 = 0.0f, y1 = 0.0f;
        int j = 0;
        for (; j + 3 < deg; j += 4) {
            int s0 = adj_src[s + j], s1 = adj_src[s + j + 1];
            int s2 = adj_src[s + j + 2], s3 = adj_src[s + j + 3];
            f16x2 qa = ((const f16x2*)Q)[(size_t)s0 * 64 + lane];
            f16x2 qb = ((const f16x2*)Q)[(size_t)s1 * 64 + lane];
            f16x2 qc = ((const f16x2*)Q)[(size_t)s2 * 64 + lane];
            f16x2 qd = ((const f16x2*)Q)[(size_t)s3 * 64 + lane];
            x0 += fmaxf(p0 + (float)qa.x, 0.0f);
            x1 += fmaxf(p1 + (float)qa.y, 0.0f);
            y0 += fmaxf(p0 + (float)qb.x, 0.0f);
            y1 += fmaxf(p1 + (float)qb.y, 0.0f);
            x0 += fmaxf(p0 + (float)qc.x, 0.0f);
            x1 += fmaxf(p1 + (float)qc.y, 0.0f);
            y0 += fmaxf(p0 + (float)qd.x, 0.0f);
            y1 += fmaxf(p1 + (float)qd.y, 0.0f);
        }
        for (; j < deg; ++j) {
            int s0 = adj_src[s + j];
            f16x2 qa = ((const f16x2*)Q)[(size_t)s0 * 64 + lane];
            x0 += fmaxf(p0 + (float)qa.x, 0.0f);
            x1 += fmaxf(p1 + (float)qa.y, 0.0f);
        }
        float sc = 1.0f / (float)deg;
        a0 = (x0 + y0) * sc;
        a1 = (x1 + y1) * sc;
    }
    f16x2 o;
    o.x = (f16)a0;
    o.y = (f16)a1;
    ((f16x2*)hbar)[(size_t)w * 64 + lane] = o;
}

// ---------------- fused: 2-layer MLP (K1 -> relu -> 128) + P/Q GEMMs on the output
// e' = mlp2(in); P = e'@W1a + bP; Q = e'@W1b.  One 64-row tile per block.
template <int K1, bool RELU_OUT>
__global__ __launch_bounds__(256, 2) void mlp2pq_kernel(
    const f16* __restrict__ in0, const f16* __restrict__ in1,
    const f16* __restrict__ w1t, const float* __restrict__ b1,
    const f16* __restrict__ w2t, const float* __restrict__ b2,
    f16* __restrict__ oute,
    const f16* __restrict__ wpq, const float* __restrict__ bP,
    f16* __restrict__ P, f16* __restrict__ Q, int numRows) {
    constexpr int KC1 = K1 / 32;
    constexpr int SA = K1 + 8;
    constexpr int SH = 136;
    constexpr int ABY = 64 * SA * 2;
    constexpr int HEBY = 64 * SH * 2 * 2;  // Hbuf + Ebuf
    constexpr int BYTES = ABY > HEBY ? ABY : HEBY;
    __shared__ __align__(16) char U[BYTES];
    f16* Abuf = (f16*)U;
    f16* Hbuf = (f16*)U;                    // aliases Abuf (dead after GEMM1)
    f16* Ebuf = (f16*)(U + 64 * SH * 2);    // disjoint from Hbuf

    const int t = threadIdx.x;
    const int lane = t & 63, wave = t >> 6;
    const int quad = lane >> 4, mn = lane & 15;
    const int n0 = wave * 32;
    const int rbase = blockIdx.x << 6;

    // ---- stage A-tile
    constexpr int UPR = K1 / 8;
    constexpr int USH = (K1 == 256) ? 5 : 3;
#pragma unroll
    for (int it = 0; it < (64 * UPR) / 256; ++it) {
        int u = it * 256 + t;
        int row = u >> USH;
        int k = (u & (UPR - 1)) * 8;
        int gr = rbase + row;
        half8 v = {};
        if (gr < numRows) {
            const f16* src;
            if constexpr (K1 == 64)
                src = in0 + (size_t)gr * 64 + k;
            else
                src = (k < 128) ? (in0 + (size_t)gr * 128 + k)
                                : (in1 + (size_t)gr * 128 + (k - 128));
            v = *(const half8*)src;
        }
        *(half8*)(Abuf + row * SA + k) = v;
    }

    // ---- GEMM1 weights (live range ends after GEMM1)
    {
        half8 w1f[KC1][2];
#pragma unroll
        for (int kc = 0; kc < KC1; ++kc)
#pragma unroll
            for (int nt = 0; nt < 2; ++nt)
                w1f[kc][nt] = *(const half8*)(w1t + (size_t)(n0 + nt * 16 + mn) * K1 + kc * 32 + quad * 8);
        float b1c[2] = {b1[n0 + mn], b1[n0 + 16 + mn]};
        __syncthreads();

        f32x4 acc[4][2];
#pragma unroll
        for (int mt = 0; mt < 4; ++mt) {
            acc[mt][0] = (f32x4){b1c[0], b1c[0], b1c[0], b1c[0]};
            acc[mt][1] = (f32x4){b1c[1], b1c[1], b1c[1], b1c[1]};
        }
#pragma unroll
        for (int kc = 0; kc < KC1; ++kc) {
            half8 af[4];
#pragma unroll
            for (int mt = 0; mt < 4; ++mt)
                af[mt] = *(const half8*)(Abuf + (mt * 16 + mn) * SA + kc * 32 + quad * 8);
#pragma unroll
            for (int mt = 0; mt < 4; ++mt) {
                acc[mt][0] = __builtin_amdgcn_mfma_f32_16x16x32_f16(af[mt], w1f[kc][0], acc[mt][0], 0, 0, 0);
                acc[mt][1] = __builtin_amdgcn_mfma_f32_16x16x32_f16(af[mt], w1f[kc][1], acc[mt][1], 0, 0, 0);
            }
        }
        __syncthreads();  // Abuf reads complete before aliased Hbuf writes
#pragma unroll
        for (int mt = 0; mt < 4; ++mt)
#pragma unroll
            for (int nt = 0; nt < 2; ++nt)
#pragma unroll
                for (int r = 0; r < 4; ++r)
                    Hbuf[(mt * 16 + quad * 4 + r) * SH + n0 + nt * 16 + mn] =
                        (f16)fmaxf(acc[mt][nt][r], 0.0f);
        __syncthreads();
    }

    // ---- GEMM2 -> e' (store global + Ebuf)
    {
        half8 w2f[4][2];
#pragma unroll
        for (int kc = 0; kc < 4; ++kc)
#pragma unroll
            for (int nt = 0; nt < 2; ++nt)
                w2f[kc][nt] = *(const half8*)(w2t + (size_t)(n0 + nt * 16 + mn) * 128 + kc * 32 + quad * 8);
        float b2c[2] = {b2[n0 + mn], b2[n0 + 16 + mn]};

        f32x4 acc2[4][2];
#pragma unroll
        for (int mt = 0; mt < 4; ++mt) {
            acc2[mt][0] = (f32x4){b2c[0], b2c[0], b2c[0], b2c[0]};
            acc2[mt][1] = (f32x4){b2c[1], b2c[1], b2c[1], b2c[1]};
        }
#pragma unroll
        for (int kc = 0; kc < 4; ++kc) {
            half8 af[4];
#pragma unroll
            for (int mt = 0; mt < 4; ++mt)
                af[mt] = *(const half8*)(Hbuf + (mt * 16 + mn) * SH + kc * 32 + quad * 8);
#pragma unroll
            for (int mt = 0; mt < 4; ++mt) {
                acc2[mt][0] = __builtin_amdgcn_mfma_f32_16x16x32_f16(af[mt], w2f[kc][0], acc2[mt][0], 0, 0, 0);
                acc2[mt][1] = __builtin_amdgcn_mfma_f32_16x16x32_f16(af[mt], w2f[kc][1], acc2[mt][1], 0, 0, 0);
            }
        }
        // Ebuf (disjoint from Hbuf) + global store; no barrier needed before Ebuf writes
#pragma unroll
        for (int mt = 0; mt < 4; ++mt)
#pragma unroll
            for (int nt = 0; nt < 2; ++nt)
#pragma unroll
                for (int r = 0; r < 4; ++r) {
                    float v = acc2[mt][nt][r];
                    if constexpr (RELU_OUT) v = fmaxf(v, 0.0f);
                    f16 hv = (f16)v;
                    int lr = mt * 16 + quad * 4 + r;
                    Ebuf[lr * SH + n0 + nt * 16 + mn] = hv;
                    int gr = rbase + lr;
                    if (gr < numRows) oute[(size_t)gr * 128 + n0 + nt * 16 + mn] = hv;
                }
        __syncthreads();
    }

    // ---- P GEMM (K=128 on e')
    {
        half8 wpa[4][2];
#pragma unroll
        for (int kc = 0; kc < 4; ++kc)
#pragma unroll
            for (int nt = 0; nt < 2; ++nt)
                wpa[kc][nt] = *(const half8*)(wpq + (size_t)(n0 + nt * 16 + mn) * 128 + kc * 32 + quad * 8);
        float bpc[2] = {bP[n0 + mn], bP[n0 + 16 + mn]};
        f32x4 accp[4][2];
#pragma unroll
        for (int mt = 0; mt < 4; ++mt) {
            accp[mt][0] = (f32x4){bpc[0], bpc[0], bpc[0], bpc[0]};
            accp[mt][1] = (f32x4){bpc[1], bpc[1], bpc[1], bpc[1]};
        }
#pragma unroll
        for (int kc = 0; kc < 4; ++kc) {
            half8 af[4];
#pragma unroll
            for (int mt = 0; mt < 4; ++mt)
                af[mt] = *(const half8*)(Ebuf + (mt * 16 + mn) * SH + kc * 32 + quad * 8);
#pragma unroll
            for (int mt = 0; mt < 4; ++mt) {
                accp[mt][0] = __builtin_amdgcn_mfma_f32_16x16x32_f16(af[mt], wpa[kc][0], accp[mt][0], 0, 0, 0);
                accp[mt][1] = __builtin_amdgcn_mfma_f32_16x16x32_f16(af[mt], wpa[kc][1], accp[mt][1], 0, 0, 0);
            }
        }
#pragma unroll
        for (int mt = 0; mt < 4; ++mt)
#pragma unroll
            for (int nt = 0; nt < 2; ++nt)
#pragma unroll
                for (int r = 0; r < 4; ++r) {
                    int gr = rbase + mt * 16 + quad * 4 + r;
                    if (gr < numRows)
                        P[(size_t)gr * 128 + n0 + nt * 16 + mn] = (f16)accp[mt][nt][r];
                }
    }

    // ---- Q GEMM (K=128 on e', no bias)
    {
        half8 wpb[4][2];
#pragma unroll
        for (int kc = 0; kc < 4; ++kc)
#pragma unroll
            for (int nt = 0; nt < 2; ++nt)
                wpb[kc][nt] = *(const half8*)(wpq + 16384 + (size_t)(n0 + nt * 16 + mn) * 128 + kc * 32 + quad * 8);
        f32x4 accq[4][2];
#pragma unroll
        for (int mt = 0; mt < 4; ++mt) {
            accq[mt][0] = (f32x4){0.0f, 0.0f, 0.0f, 0.0f};
            accq[mt][1] = (f32x4){0.0f, 0.0f, 0.0f, 0.0f};
        }
#pragma unroll
        for (int kc = 0; kc < 4; ++kc) {
            half8 af[4];
#pragma unroll
            for (int mt = 0; mt < 4; ++mt)
                af[mt] = *(const half8*)(Ebuf + (mt * 16 + mn) * SH + kc * 32 + quad * 8);
#pragma unroll
            for (int mt = 0; mt < 4; ++mt) {
                accq[mt][0] = __builtin_amdgcn_mfma_f32_16x16x32_f16(af[mt], wpb[kc][0], accq[mt][0], 0, 0, 0);
                accq[mt][1] = __builtin_amdgcn_mfma_f32_16x16x32_f16(af[mt], wpb[kc][1], accq[mt][1], 0, 0, 0);
            }
        }
#pragma unroll
        for (int mt = 0; mt < 4; ++mt)
#pragma unroll
            for (int nt = 0; nt < 2; ++nt)
#pragma unroll
                for (int r = 0; r < 4; ++r) {
                    int gr = rbase + mt * 16 + quad * 4 + r;
                    if (gr < numRows)
                        Q[(size_t)gr * 128 + n0 + nt * 16 + mn] = (f16)accq[mt][nt][r];
                }
    }
}

// ---------------- predictor tail: h1=relu(Pp[i]+Qp[j]); h2=relu(h1@W2+b2); logit=h2@W3+b3
__global__ __launch_bounds__(256, 2) void pred_tail(
    const f16* __restrict__ Pp, const f16* __restrict__ Qp,
    const int* __restrict__ ci, const int* __restrict__ cj,
    const f16* __restrict__ w2t, const float* __restrict__ b2,
    const float* __restrict__ w3, const float* __restrict__ b3,
    float* __restrict__ outProb, float* __restrict__ outLogit, int numRows) {
    constexpr int SA = 136;  // f16
    constexpr int SO = 133;  // f32
    constexpr int BYTES = (64 * SO * 4 > 64 * SA * 2) ? 64 * SO * 4 : 64 * SA * 2;
    __shared__ __align__(16) char U[BYTES];
    f16* Abuf = (f16*)U;
    float* Obuf = (float*)U;
    __shared__ float w3s[128];
    __shared__ float psum[256];

    const int t = threadIdx.x;
    const int lane = t & 63, wave = t >> 6;
    const int quad = lane >> 4, mn = lane & 15;
    const int n0 = wave * 32;

    if (t < 128) w3s[t] = w3[t];
    float b3v = b3[0];

    half8 wf[4][2];
#pragma unroll
    for (int kc = 0; kc < 4; ++kc)
#pragma unroll
        for (int nt = 0; nt < 2; ++nt)
            wf[kc][nt] = *(const half8*)(w2t + (size_t)(n0 + nt * 16 + mn) * 128 + kc * 32 + quad * 8);
    float b2c[2] = {b2[n0 + mn], b2[n0 + 16 + mn]};

    const int nTiles = (numRows + 63) >> 6;
    for (int tile = blockIdx.x; tile < nTiles; tile += gridDim.x) {
        const int rbase = tile << 6;
#pragma unroll
        for (int it = 0; it < 4; ++it) {
            int u = it * 256 + t;
            int row = u >> 4;
            int k = (u & 15) * 8;
            int gr = rbase + row;
            half8 v = {};
            if (gr < numRows) {
                int i = ci[gr], j = cj[gr];
                half8 a = *(const half8*)(Pp + (size_t)i * 128 + k);
                half8 b = *(const half8*)(Qp + (size_t)j * 128 + k);
#pragma unroll
                for (int x = 0; x < 8; ++x)
                    v[x] = (f16)fmaxf((float)a[x] + (float)b[x], 0.0f);
            }
            *(half8*)(Abuf + row * SA + k) = v;
        }
        __syncthreads();

        f32x4 acc[4][2];
#pragma unroll
        for (int mt = 0; mt < 4; ++mt) {
            acc[mt][0] = (f32x4){b2c[0], b2c[0], b2c[0], b2c[0]};
            acc[mt][1] = (f32x4){b2c[1], b2c[1], b2c[1], b2c[1]};
        }
#pragma unroll
        for (int kc = 0; kc < 4; ++kc) {
            half8 af[4];
#pragma unroll
            for (int mt = 0; mt < 4; ++mt)
                af[mt] = *(const half8*)(Abuf + (mt * 16 + mn) * SA + kc * 32 + quad * 8);
#pragma unroll
            for (int mt = 0; mt < 4; ++mt) {
                acc[mt][0] = __builtin_amdgcn_mfma_f32_16x16x32_f16(af[mt], wf[kc][0], acc[mt][0], 0, 0, 0);
                acc[mt][1] = __builtin_amdgcn_mfma_f32_16x16x32_f16(af[mt], wf[kc][1], acc[mt][1], 0, 0, 0);
            }
        }
        __syncthreads();  // Abuf reads done before aliased Obuf writes
#pragma unroll
        for (int mt = 0; mt < 4; ++mt)
#pragma unroll
            for (int nt = 0; nt < 2; ++nt)
#pragma unroll
                for (int r = 0; r < 4; ++r)
                    Obuf[(mt * 16 + quad * 4 + r) * SO + n0 + nt * 16 + mn] =
                        fmaxf(acc[mt][nt][r], 0.0f);
        __syncthreads();
        {
            int row = t & 63, q4 = t >> 6;
            float s = 0.0f;
#pragma unroll
            for (int i = 0; i < 32; ++i)
                s += Obuf[row * SO + q4 * 32 + i] * w3s[q4 * 32 + i];
            psum[t] = s;
        }
        __syncthreads();
        if (t < 64) {
            int gr = rbase + t;
            if (gr < numRows) {
                float lg = psum[t] + psum[t + 64] + psum[t + 128] + psum[t + 192] + b3v;
                outLogit[gr] = lg;
                outProb[gr] = 1.0f / (1.0f + expf(-lg));
            }
        }
        __syncthreads();
    }
}

// ---------------- host ----------------
extern "C" void kernel_launch(void* const* d_in, const int* in_sizes, int n_in,
                              void* d_out, int out_size, void* d_ws, size_t ws_size,
                              hipStream_t stream) {
    const float* edge_features = (const float*)d_in[0];
    const int* adj_dst = (const int*)d_in[1];
    const int* adj_src = (const int*)d_in[2];
    const int* cand_i = (const int*)d_in[3];
    const int* cand_j = (const int*)d_in[4];
    const float* enc_W1 = (const float*)d_in[5];
    const float* enc_b1 = (const float*)d_in[6];
    const float* enc_W2 = (const float*)d_in[7];
    const float* enc_b2 = (const float*)d_in[8];
    const float* msg_W1 = (const float*)d_in[9];
    const float* msg_b1 = (const float*)d_in[10];
    const float* msg_W2 = (const float*)d_in[11];
    const float* msg_b2 = (const float*)d_in[12];
    const float* upd_W1 = (const float*)d_in[13];
    const float* upd_b1 = (const float*)d_in[14];
    const float* upd_W2 = (const float*)d_in[15];
    const float* upd_b2 = (const float*)d_in[16];
    const float* pred_W1 = (const float*)d_in[17];
    const float* pred_b1 = (const float*)d_in[18];
    const float* pred_W2 = (const float*)d_in[19];
    const float* pred_b2 = (const float*)d_in[20];
    const float* pred_W3 = (const float*)d_in[21];
    const float* pred_b3 = (const float*)d_in[22];

    char* ws = (char*)d_ws;
    size_t off = 0;
    auto alloc = [&](size_t bytes) -> void* {
        void* p = ws + off;
        off = (off + bytes + 255) & ~(size_t)255;
        return p;
    };
    f16* wt = (f16*)alloc((size_t)TOTAL_WT * 2);
    float* fbias = (float*)alloc(3 * 128 * 4);
    f16* xb = (f16*)alloc((size_t)NE * 64 * 2);
    f16* eA = (f16*)alloc((size_t)NE * 128 * 2);
    f16* eB = (f16*)alloc((size_t)NE * 128 * 2);
    f16* Pb = (f16*)alloc((size_t)NE * 128 * 2);
    f16* Qb = (f16*)alloc((size_t)NE * 128 * 2);
    f16* hbar = (f16*)alloc((size_t)NE * 128 * 2);
    int* degI = (int*)alloc((size_t)NE * 4);
    int* segStart = (int*)alloc((size_t)NE * 4);

    WTArgs wa;
    int idx = 0, c = 0;
    auto addj = [&](const float* s, int K, int o, int st) {
        wa.src[idx] = s; wa.K[idx] = K; wa.dstOff[idx] = o;
        wa.dstStride[idx] = st; wa.cum[idx] = c;
        c += K * 128; idx++;
    };
    addj(enc_W1, 64, OFF_ENC1, 64);
    addj(enc_W2, 128, OFF_ENC2, 128);
    for (int l = 0; l < 3; ++l) addj(msg_W1 + (size_t)l * 32768, 128, OFF_MSGPQ + l * 32768, 128);
    for (int l = 0; l < 3; ++l) addj(msg_W1 + (size_t)l * 32768 + 16384, 128, OFF_MSGPQ + l * 32768 + 16384, 128);
    for (int l = 0; l < 3; ++l) addj(upd_W1 + (size_t)l * 32768, 128, OFF_UPD1 + l * 32768, 256);
    for (int l = 0; l < 3; ++l) addj(upd_W2 + (size_t)l * 16384, 128, OFF_UPD2 + l * 16384, 128);
    addj(pred_W1, 128, OFF_PREDPQ, 128);
    addj(pred_W1 + 16384, 128, OFF_PREDPQ + 16384, 128);
    addj(pred_W2, 128, OFF_PREDW2, 128);
    for (int i = idx; i <= 20; ++i) wa.cum[i] = c;  // c == 270336

    const int prepN = 270336 + NE * 16 + NE;
    prep_kernel<<<(prepN + 255) / 256, 256, 0, stream>>>(wa, edge_features, wt, xb, degI);
    fuse_w<<<(3 * 128 * 129 + 255) / 256, 256, 0, stream>>>(msg_W2, msg_b2, upd_W1, upd_b1, wt, fbias);
    degseg_kernel<<<(NA + 255) / 256, 256, 0, stream>>>(adj_dst, degI, segStart);

    const int tilesNE = (NE + 63) / 64;  // 782

    // encoder fused with layer-0 P/Q
    mlp2pq_kernel<64, false><<<tilesNE, 256, 0, stream>>>(
        xb, nullptr, wt + OFF_ENC1, enc_b1, wt + OFF_ENC2, enc_b2, eA,
        wt + OFF_MSGPQ, msg_b1, Pb, Qb, NE);

    f16* cur = eA;
    f16* nxt = eB;
    for (int l = 0; l < 3; ++l) {
        pair_agg<<<(NE + 3) / 4, 256, 0, stream>>>(Pb, Qb, adj_src, segStart, degI, hbar);
        // update fused with next-stage P/Q (msg layer l+1, or predictor for l==2)
        const f16* wpq = (l < 2) ? (wt + OFF_MSGPQ + (l + 1) * 32768) : (wt + OFF_PREDPQ);
        const float* bP = (l < 2) ? (msg_b1 + (l + 1) * 128) : pred_b1;
        mlp2pq_kernel<256, true><<<tilesNE, 256, 0, stream>>>(
            cur, hbar, wt + OFF_UPD1 + l * 32768, fbias + l * 128,
            wt + OFF_UPD2 + l * 16384, upd_b2 + l * 128, nxt,
            wpq, bP, Pb, Qb, NE);
        f16* tmp = cur; cur = nxt; nxt = tmp;
    }

    float* outP = (float*)d_out;
    pred_tail<<<(NC + 63) / 64, 256, 0, stream>>>(
        Pb, Qb, cand_i, cand_j, wt + OFF_PREDW2, pred_b2, pred_W3, pred_b3,
        outP, outP + NC, NC);

    (void)in_sizes; (void)n_in; (void)out_size; (void)ws_size;
}